// Round 7
// baseline (52.491 us; speedup 1.0000x reference)
//
#include <hip/hip_runtime.h>
#include <hip/hip_bf16.h>
#include <hip/hip_fp16.h>

typedef __attribute__((ext_vector_type(8))) short short8;   // 8 x bf16 (4 VGPRs)
typedef __attribute__((ext_vector_type(4))) float f32x4;    // MFMA accumulator

#define OUT_F  11008
#define IN_F   4096
#define BN     64
#define SPLITS 4
#define KSTEPS 8              // 128-wide K steps per split (4*8*128 = 4096)
#define NB     (OUT_F / BN)   // 172
#define NGRP   (OUT_F * IN_F / 128)   // 352256 quant groups

// workspace layout (bytes)
#define WS_RNG  0                        // float2 {xmin, dd}, TRANSPOSED [kb][n]: 2818048 B
#define WS_XB   (NGRP * 8)               // bf16 x: 32*4096*2 = 262144 B
#define WS_PART (WS_XB + 32 * IN_F * 2)  // split-K partials: 4*32*11008*4 B

// ---------- helpers ----------
static __device__ __forceinline__ uint pack2_bf16(float a, float b) {
    __hip_bfloat162 h = __float22bfloat162_rn(make_float2(a, b));
    uint u;
    __builtin_memcpy(&u, &h, 4);
    return u;
}

static __device__ __forceinline__ float bf16_to_f(ushort u) {
    return __uint_as_float(((uint)u) << 16);
}

// dequant 8 weights (2 packed ints, low bytes) -> short8 bf16
static __device__ __forceinline__ short8 dq8(int2 p, float xmin, float dd) {
    uint u0 = pack2_bf16(fmaf((float)(p.x & 3), dd, xmin),
                         fmaf((float)((p.x >> 2) & 3), dd, xmin));
    uint u1 = pack2_bf16(fmaf((float)((p.x >> 4) & 3), dd, xmin),
                         fmaf((float)((p.x >> 6) & 3), dd, xmin));
    uint u2 = pack2_bf16(fmaf((float)(p.y & 3), dd, xmin),
                         fmaf((float)((p.y >> 2) & 3), dd, xmin));
    uint u3 = pack2_bf16(fmaf((float)((p.y >> 4) & 3), dd, xmin),
                         fmaf((float)((p.y >> 6) & 3), dd, xmin));
    uint4 q = make_uint4(u0, u1, u2, u3);
    short8 r;
    __builtin_memcpy(&r, &q, 16);
    return r;
}

// ---------- kernel 1: x->bf16 | detect dtype + decode ranges (transposed) ----------
__global__ __launch_bounds__(256)
void prep_kernel(const float* __restrict__ x,
                 const void* __restrict__ rr,
                 char* __restrict__ ws) {
    const int b = blockIdx.x;
    const int t = threadIdx.x;
    if (b < 128) {
        // x: 32*4096 f32 -> bf16; 4/thread; 128*256*4 = 131072
        const int i = b * 256 + t;
        const float4 v = ((const float4*)x)[i];
        ushort4 o;
        __hip_bfloat16 h0 = __float2bfloat16(v.x);
        __hip_bfloat16 h1 = __float2bfloat16(v.y);
        __hip_bfloat16 h2 = __float2bfloat16(v.z);
        __hip_bfloat16 h3 = __float2bfloat16(v.w);
        __builtin_memcpy(&o.x, &h0, 2);
        __builtin_memcpy(&o.y, &h1, 2);
        __builtin_memcpy(&o.z, &h2, 2);
        __builtin_memcpy(&o.w, &h3, 2);
        ((ushort4*)(ws + WS_XB))[i] = o;
        return;
    }
    // ---- block-local dtype detection (identical logic to passing rounds) ----
    __shared__ int s_viol[3];
    __shared__ int s_max[3];
    __shared__ int s_fmt;
    if (t < 3) { s_viol[t] = 0; s_max[t] = 0; }
    __syncthreads();
    {
        const int g = 1024 + t;   // f32-view reads bytes [8192,10240): in-bounds for all fmts
        const uint   ru = ((const uint*)rr)[g];
        const float2 rf = ((const float2*)rr)[g];
        int viol[3]; float mx[3];
        {   // h0: fp16 pairs
            __half2 h; __builtin_memcpy(&h, &ru, 4);
            const float a = __half2float(h.x), c = __half2float(h.y);
            viol[0] = !(fabsf(a) < 1.f && fabsf(c) < 1.f && a <= c);
            mx[0] = fabsf(c);
        }
        {   // h1: bf16 pairs
            const float a = bf16_to_f((ushort)(ru & 0xffff));
            const float c = bf16_to_f((ushort)(ru >> 16));
            viol[1] = !(fabsf(a) < 1.f && fabsf(c) < 1.f && a <= c);
            mx[1] = fabsf(c);
        }
        {   // h2: f32 pairs
            viol[2] = !(fabsf(rf.x) < 1.f && fabsf(rf.y) < 1.f && rf.x <= rf.y);
            mx[2] = fabsf(rf.y);
        }
#pragma unroll
        for (int h = 0; h < 3; ++h) {
            if (viol[h]) atomicOr(&s_viol[h], 1);
            atomicMax(&s_max[h], __float_as_int(mx[h]));   // mx >= 0: int-monotone
        }
    }
    __syncthreads();
    if (t == 0) {
        const float lo = 0.02f;
        int f = 0;
        if      (!s_viol[2] && __int_as_float(s_max[2]) > lo) f = 2;
        else if (!s_viol[1] && __int_as_float(s_max[1]) > lo) f = 1;
        s_fmt = f;
    }
    __syncthreads();
    const int fmt = s_fmt;

    // ---- decode this block's 32 rows x 32 kb -> TRANSPOSED rngT[kb][n] ----
    // thread (n_local = t&31, kbg = t>>5) handles kb = kbg*4..+4 of row n0+n_local.
    // Writes: 32 consecutive float2 per (kb) = 256-B contiguous chunks.
    const int n0 = (b - 128) * 32;          // 344 blocks * 32 rows = 11008 rows
    const int nl = t & 31;
    const int kbg = t >> 5;
    float2* rngT = (float2*)(ws + WS_RNG);
#pragma unroll
    for (int jj = 0; jj < 4; ++jj) {
        const int kb = kbg * 4 + jj;
        const int g  = (n0 + nl) * 32 + kb;
        float xmin, xmax;
        if (fmt == 2) {
            const float2 f = ((const float2*)rr)[g];
            xmin = f.x; xmax = f.y;
        } else if (fmt == 1) {
            const uint u = ((const uint*)rr)[g];
            xmin = bf16_to_f((ushort)(u & 0xffff));
            xmax = bf16_to_f((ushort)(u >> 16));
        } else {
            uint u = ((const uint*)rr)[g];
            __half2 h; __builtin_memcpy(&h, &u, 4);
            xmin = __half2float(h.x); xmax = __half2float(h.y);
        }
        rngT[kb * OUT_F + n0 + nl] = make_float2(xmin, (xmax - xmin) * (1.0f / 3.0f));
    }
}

// ---------- kernel 2: GEMM, register-direct dequant. NO LDS, NO barriers ----------
__global__ __launch_bounds__(256, 3)
void gemm_kernel(const int* __restrict__ packed,
                 const char* __restrict__ ws,
                 float* __restrict__ part) {
    const int nb   = blockIdx.x;   // 0..171 (64 output cols)
    const int s    = blockIdx.y;   // 0..3   (K split: 1024 each)
    const int t    = threadIdx.x;
    const int lane = t & 63;
    const int wv   = t >> 6;

    const float2* rngT = (const float2*)(ws + WS_RNG);
    const ushort* xb   = (const ushort*)(ws + WS_XB);

    const int r = lane & 15;          // MFMA col within 16
    const int j = lane >> 4;          // k-slice group (k = j*8..j*8+8)
    const int nrow = (wv << 4) | r;   // W row this lane feeds (wave owns 16 rows)
    const int n    = nb * BN + nrow;

    // per-lane W source: row n, split s; step/kc offsets are compile-time imms
    const char* wp = (const char*)packed + (size_t)n * 4096 + s * 1024 + j * 8;
    // A source: rows r (acc0) and r+16 (acc1), col base s*1024 + j*8 (bf16 elems)
    const ushort* xa = xb + r * IN_F + s * 1024 + j * 8;
    // ranges: transposed — wave's 16 rows are 16 consecutive float2 (128 B)
    const float2* rb = rngT + n;

    f32x4 acc0 = {0.f, 0.f, 0.f, 0.f};
    f32x4 acc1 = {0.f, 0.f, 0.f, 0.f};

#pragma unroll
    for (int step = 0; step < KSTEPS; ++step) {
        const float2 rc = rb[(size_t)(s * KSTEPS + step) * OUT_F];

        short8 a0[4], a1[4];
#pragma unroll
        for (int kc = 0; kc < 4; ++kc) {
            a0[kc] = *(const short8*)(xa + step * 128 + kc * 32);
            a1[kc] = *(const short8*)(xa + 16 * IN_F + step * 128 + kc * 32);
        }
#pragma unroll
        for (int kc = 0; kc < 4; ++kc) {
            const int2 pq = *(const int2*)(wp + step * 128 + kc * 32);
            const short8 bf = dq8(pq, rc.x, rc.y);
            acc0 = __builtin_amdgcn_mfma_f32_16x16x32_bf16(a0[kc], bf, acc0, 0, 0, 0);
            acc1 = __builtin_amdgcn_mfma_f32_16x16x32_bf16(a1[kc], bf, acc1, 0, 0, 0);
        }
    }

    // ---- epilogue: split-K partial stores ----
    // C/D layout col=lane&15, row=(lane>>4)*4+reg (m89-verified)
    float* pout = part + (size_t)s * (32 * OUT_F);
    const int col = n;
    const int r0  = j << 2;
#pragma unroll
    for (int v = 0; v < 4; ++v) {
        pout[(r0 + v) * OUT_F + col]      = acc0[v];
        pout[(16 + r0 + v) * OUT_F + col] = acc1[v];
    }
}

// ---------- kernel 3: out = bias + sum of split-K partials ----------
__global__ __launch_bounds__(256)
void reduce_kernel(const float* __restrict__ part,
                   const float* __restrict__ bias,
                   float* __restrict__ out) {
    const int i = blockIdx.x * 256 + threadIdx.x;   // 0..88063 float4 units
    const int n4 = i % 2752;                        // 11008/4
    const float4* p4 = (const float4*)part;
    float4 a = ((const float4*)bias)[n4];
#pragma unroll
    for (int ss = 0; ss < SPLITS; ++ss) {
        const float4 v = p4[ss * 88064 + i];
        a.x += v.x; a.y += v.y; a.z += v.z; a.w += v.w;
    }
    ((float4*)out)[i] = a;
}

extern "C" void kernel_launch(void* const* d_in, const int* in_sizes, int n_in,
                              void* d_out, int out_size, void* d_ws, size_t ws_size,
                              hipStream_t stream) {
    const float* x      = (const float*)d_in[0];
    const int*   packed = (const int*)d_in[1];
    const void*  rr     = (const void*)d_in[2];
    const float* bias   = (const float*)d_in[3];
    float*       out    = (float*)d_out;
    char*        ws     = (char*)d_ws;
    float*       part   = (float*)(ws + WS_PART);

    prep_kernel<<<472, 256, 0, stream>>>(x, rr, ws);
    gemm_kernel<<<dim3(NB, SPLITS), 256, 0, stream>>>(packed, ws, part);
    reduce_kernel<<<344, 256, 0, stream>>>(part, bias, out);
}

// Round 8
// 31.821 us; speedup vs baseline: 1.6496x; 1.6496x over previous
//
#include <hip/hip_runtime.h>
#include <hip/hip_bf16.h>
#include <hip/hip_fp16.h>

typedef __attribute__((ext_vector_type(8))) short short8;   // 8 x bf16 (4 VGPRs)
typedef __attribute__((ext_vector_type(4))) float f32x4;    // MFMA accumulator

#define OUT_F  11008
#define IN_F   4096
#define BN     64
#define SPLITS 4
#define KSTEPS 8              // 128-wide K steps per split (4*8*128 = 4096)
#define NB     (OUT_F / BN)   // 172
#define WB     8192           // one RAW W buffer: 64 rows x 128 B
#define AB     8192           // one A buffer: 32 rows x 128 bf16 (swizzled)

// ---------- helpers ----------
static __device__ __forceinline__ uint pack2_bf16(float a, float b) {
    __hip_bfloat162 h = __float22bfloat162_rn(make_float2(a, b));
    uint u;
    __builtin_memcpy(&u, &h, 4);
    return u;
}

static __device__ __forceinline__ float bf16_to_f(ushort u) {
    return __uint_as_float(((uint)u) << 16);
}

// dequant 8 weights (2 packed ints, low bytes) -> short8 bf16
static __device__ __forceinline__ short8 dq8(int2 p, float xmin, float dd) {
    uint u0 = pack2_bf16(fmaf((float)(p.x & 3), dd, xmin),
                         fmaf((float)((p.x >> 2) & 3), dd, xmin));
    uint u1 = pack2_bf16(fmaf((float)((p.x >> 4) & 3), dd, xmin),
                         fmaf((float)((p.x >> 6) & 3), dd, xmin));
    uint u2 = pack2_bf16(fmaf((float)(p.y & 3), dd, xmin),
                         fmaf((float)((p.y >> 2) & 3), dd, xmin));
    uint u3 = pack2_bf16(fmaf((float)((p.y >> 4) & 3), dd, xmin),
                         fmaf((float)((p.y >> 6) & 3), dd, xmin));
    uint4 q = make_uint4(u0, u1, u2, u3);
    short8 r;
    __builtin_memcpy(&r, &q, 16);
    return r;
}

static __device__ __forceinline__ void rng_decode(uint ru, float2 rf, int fmt,
                                                  float& xmin, float& dd) {
    float xmax;
    if (fmt == 2) {
        xmin = rf.x; xmax = rf.y;
    } else if (fmt == 1) {
        xmin = bf16_to_f((ushort)(ru & 0xffff));
        xmax = bf16_to_f((ushort)(ru >> 16));
    } else {
        __half2 h;
        __builtin_memcpy(&h, &ru, 4);
        xmin = __half2float(h.x); xmax = __half2float(h.y);
    }
    dd = (xmax - xmin) * (1.0f / 3.0f);
}

static __device__ __forceinline__ void gload16(const void* g, void* l) {
    __builtin_amdgcn_global_load_lds((const __attribute__((address_space(1))) void*)g,
                                     (__attribute__((address_space(3))) void*)l,
                                     16, 0, 0);
}

// ---------- kernel 1: fused detect + raw-stage + dequant-on-read GEMM ----------
__global__ __launch_bounds__(256, 3)
void gemm_kernel(const float* __restrict__ x,
                 const int* __restrict__ packed,
                 const void* __restrict__ rr,
                 float* __restrict__ part) {
    const int nb   = blockIdx.x;   // 0..171 (64 output cols)
    const int s    = blockIdx.y;   // 0..3   (K split: 1024 each)
    const int t    = threadIdx.x;
    const int lane = t & 63;
    const int wv   = t >> 6;

    __shared__ __align__(16) char lds[3 * WB + 2 * AB];   // 40 KiB
    __shared__ int s_viol[3];
    __shared__ int s_max[3];
    __shared__ int s_fmt;

    // ---- block-local range-dtype detection (verbatim from passing rounds) ----
    if (t < 3) { s_viol[t] = 0; s_max[t] = 0; }
    __syncthreads();
    {
        const int g = 1024 + t;   // f32-view reads bytes [8192,10240): in-bounds for all fmts
        const uint   ru = ((const uint*)rr)[g];
        const float2 rf = ((const float2*)rr)[g];
        int viol[3]; float mx[3];
        {   // h0: fp16 pairs
            __half2 h; __builtin_memcpy(&h, &ru, 4);
            const float a = __half2float(h.x), c = __half2float(h.y);
            viol[0] = !(fabsf(a) < 1.f && fabsf(c) < 1.f && a <= c);
            mx[0] = fabsf(c);
        }
        {   // h1: bf16 pairs
            const float a = bf16_to_f((ushort)(ru & 0xffff));
            const float c = bf16_to_f((ushort)(ru >> 16));
            viol[1] = !(fabsf(a) < 1.f && fabsf(c) < 1.f && a <= c);
            mx[1] = fabsf(c);
        }
        {   // h2: f32 pairs
            viol[2] = !(fabsf(rf.x) < 1.f && fabsf(rf.y) < 1.f && rf.x <= rf.y);
            mx[2] = fabsf(rf.y);
        }
#pragma unroll
        for (int h = 0; h < 3; ++h) {
            if (viol[h]) atomicOr(&s_viol[h], 1);
            atomicMax(&s_max[h], __float_as_int(mx[h]));
        }
    }
    __syncthreads();
    if (t == 0) {
        const float lo = 0.02f;
        int f = 0;
        if      (!s_viol[2] && __int_as_float(s_max[2]) > lo) f = 2;
        else if (!s_viol[1] && __int_as_float(s_max[1]) > lo) f = 1;
        s_fmt = f;
    }
    __syncthreads();
    const int fmt = s_fmt;   // uniform across block

    // ---- W staging: lane covers rows {wv*8 + lane>>3, +32}, 16 B each ----
    // Global source pre-swizzled within the 128-B window; LDS dest linear
    // (gload_lds: wave-uniform base + lane*16). Involution matches read XOR.
    const int sr0 = wv * 8 + (lane >> 3);
    const int sr1 = sr0 + 32;
    const char* gw0 = (const char*)packed + (size_t)(nb * BN + sr0) * 4096 + s * 1024
                      + (uint)(((lane & 7) * 16) ^ ((sr0 & 7) << 4));
    const char* gw1 = (const char*)packed + (size_t)(nb * BN + sr1) * 4096 + s * 1024
                      + (uint)(((lane & 7) * 16) ^ ((sr1 & 7) << 4));

    // ---- A staging (write): thread covers x row t>>3, 16 f32 at col (t&7)*16 ----
    const float* xsrc = x + (t >> 3) * IN_F + s * 1024 + (t & 7) * 16;
    const uint aswz = (uint)(((t >> 3) & 7) << 4);
    const uint acb  = (uint)((t & 7) * 32);

    // ---- consumers ----
    const int r = lane & 15;           // C col within 16 / A row (acc0)
    const int j = lane >> 4;           // k-slice (k = j*8 .. +8)
    const int nrow = (wv << 4) | r;    // W row this lane dequants
    const int n    = nb * BN + nrow;
    const uint arsw = (uint)((r & 7) << 4);
    const uint rsw  = (uint)((nrow & 7) << 4);
    const int rngidx = n * 32;
    const uint*   rr_u  = (const uint*)rr;
    const float2* rr_f2 = (const float2*)rr;
    const int kb0 = s * KSTEPS;

    char* wbufA = lds;                 // read target (step t)
    char* wbufB = lds + WB;            // stage target (step t+1)
    char* wbufC = lds + 2 * WB;
    char* abuf0 = lds + 3 * WB;
    char* abuf1 = abuf0 + AB;

    f32x4 acc0 = {0.f, 0.f, 0.f, 0.f};
    f32x4 acc1 = {0.f, 0.f, 0.f, 0.f};

    // ---- prologue: stage step 0 (gloads FIRST), then step-0 reg loads ----
    gload16(gw0, wbufA + wv * 1024);
    gload16(gw1, wbufA + 4096 + wv * 1024);
    uint  ruc = 0; float2 rfc = {0.f, 0.f};
    if (fmt == 2) rfc = rr_f2[rngidx + kb0];
    else          ruc = rr_u[rngidx + kb0];
    float4 xc0 = *(const float4*)(xsrc);
    float4 xc1 = *(const float4*)(xsrc + 4);
    float4 xc2 = *(const float4*)(xsrc + 8);
    float4 xc3 = *(const float4*)(xsrc + 12);

#pragma unroll 1
    for (int step = 0; step < KSTEPS; ++step) {
        // (1) stage W(t+1) -> wbufB (wrap-around at t=7: harmless reload)
        const int stn = (step + 1) & (KSTEPS - 1);
        gload16(gw0 + stn * 128, wbufB + wv * 1024);
        gload16(gw1 + stn * 128, wbufB + 4096 + wv * 1024);

        // (2) reg loads for t+1: ranges + x slice
        uint  run = 0; float2 rfn = {0.f, 0.f};
        if (fmt == 2) rfn = rr_f2[rngidx + kb0 + stn];
        else          run = rr_u[rngidx + kb0 + stn];
        const float* xs = xsrc + stn * 128;
        float4 xn0 = *(const float4*)(xs);
        float4 xn1 = *(const float4*)(xs + 4);
        float4 xn2 = *(const float4*)(xs + 8);
        float4 xn3 = *(const float4*)(xs + 12);

        // (3) pack current x slice -> A tile (bf16, swizzled)
        {
            char* at = (step & 1) ? abuf1 : abuf0;
            uint q0 = pack2_bf16(xc0.x, xc0.y), q1 = pack2_bf16(xc0.z, xc0.w);
            uint q2 = pack2_bf16(xc1.x, xc1.y), q3 = pack2_bf16(xc1.z, xc1.w);
            uint q4 = pack2_bf16(xc2.x, xc2.y), q5 = pack2_bf16(xc2.z, xc2.w);
            uint q6 = pack2_bf16(xc3.x, xc3.y), q7 = pack2_bf16(xc3.z, xc3.w);
            char* adst = at + (t >> 3) * 256;
            *(uint4*)(adst + (acb ^ aswz))        = make_uint4(q0, q1, q2, q3);
            *(uint4*)(adst + ((acb + 16) ^ aswz)) = make_uint4(q4, q5, q6, q7);
        }

        // (4) handoff: drain LDS writes; allow exactly this step's 7 VMEM ops
        //     ({2 gload, 4 xf, 1 rng} of t+1) to stay in flight across barrier.
        asm volatile("s_waitcnt lgkmcnt(0) vmcnt(7)" ::: "memory");
        __builtin_amdgcn_s_barrier();
        __builtin_amdgcn_sched_barrier(0);

        // (5) dequant-on-read + MFMA
        {
            const char* at  = (step & 1) ? abuf1 : abuf0;
            const char* as0 = at + r * 256;
            const char* as1 = as0 + 16 * 256;
            const char* wt  = wbufA + nrow * 128;
            float xmin, dd;
            rng_decode(ruc, rfc, fmt, xmin, dd);
#pragma unroll
            for (int kc = 0; kc < 4; ++kc) {
                const uint ao = (uint)((kc << 6) | (j << 4));
                short8 av0 = *(const short8*)(as0 + (ao ^ arsw));
                short8 av1 = *(const short8*)(as1 + (ao ^ arsw));
                const int2 pq = *(const int2*)(wt + ((uint)((kc << 5) | (j << 3)) ^ rsw));
                const short8 bf = dq8(pq, xmin, dd);
                acc0 = __builtin_amdgcn_mfma_f32_16x16x32_bf16(av0, bf, acc0, 0, 0, 0);
                acc1 = __builtin_amdgcn_mfma_f32_16x16x32_bf16(av1, bf, acc1, 0, 0, 0);
            }
        }

        // (6) rotate
        ruc = run; rfc = rfn;
        xc0 = xn0; xc1 = xn1; xc2 = xn2; xc3 = xn3;
        char* tmp = wbufA; wbufA = wbufB; wbufB = wbufC; wbufC = tmp;
    }

    // ---- epilogue: split-K partial stores ----
    // C/D layout col=lane&15, row=(lane>>4)*4+reg (m89-verified)
    float* pout = part + (size_t)s * (32 * OUT_F);
    const int r0 = j << 2;
#pragma unroll
    for (int v = 0; v < 4; ++v) {
        pout[(r0 + v) * OUT_F + n]      = acc0[v];
        pout[(16 + r0 + v) * OUT_F + n] = acc1[v];
    }
}

// ---------- kernel 2: out = bias + sum of split-K partials ----------
__global__ __launch_bounds__(256)
void reduce_kernel(const float* __restrict__ part,
                   const float* __restrict__ bias,
                   float* __restrict__ out) {
    const int i = blockIdx.x * 256 + threadIdx.x;   // 0..88063 float4 units
    const int n4 = i % 2752;                        // 11008/4
    const float4* p4 = (const float4*)part;
    float4 a = ((const float4*)bias)[n4];
#pragma unroll
    for (int ss = 0; ss < SPLITS; ++ss) {
        const float4 v = p4[ss * 88064 + i];
        a.x += v.x; a.y += v.y; a.z += v.z; a.w += v.w;
    }
    ((float4*)out)[i] = a;
}

extern "C" void kernel_launch(void* const* d_in, const int* in_sizes, int n_in,
                              void* d_out, int out_size, void* d_ws, size_t ws_size,
                              hipStream_t stream) {
    const float* x      = (const float*)d_in[0];
    const int*   packed = (const int*)d_in[1];
    const void*  rr     = (const void*)d_in[2];
    const float* bias   = (const float*)d_in[3];
    float*       out    = (float*)d_out;
    float*       part   = (float*)d_ws;   // 4*32*11008 f32 = 5.6 MB

    gemm_kernel<<<dim3(NB, SPLITS), 256, 0, stream>>>(x, packed, rr, part);
    reduce_kernel<<<344, 256, 0, stream>>>(part, bias, out);
}

// Round 9
// 31.778 us; speedup vs baseline: 1.6518x; 1.0013x over previous
//
#include <hip/hip_runtime.h>
#include <hip/hip_bf16.h>
#include <hip/hip_fp16.h>

typedef __attribute__((ext_vector_type(8))) short short8;   // 8 x bf16 (4 VGPRs)
typedef __attribute__((ext_vector_type(4))) float f32x4;    // MFMA accumulator

#define OUT_F  11008
#define IN_F   4096
#define BN     64
#define SPLITS 4
#define KSTEPS 8              // 128-wide K steps per split (4*8*128 = 4096)
#define NB     (OUT_F / BN)   // 172
#define WB     8192           // one RAW W buffer: 64 rows x 128 B
#define AB     8192           // one A buffer: 32 rows x 128 bf16 (swizzled)

// ---------- helpers ----------
static __device__ __forceinline__ uint pack2_bf16(float a, float b) {
    __hip_bfloat162 h = __float22bfloat162_rn(make_float2(a, b));
    uint u;
    __builtin_memcpy(&u, &h, 4);
    return u;
}

static __device__ __forceinline__ float bf16_to_f(ushort u) {
    return __uint_as_float(((uint)u) << 16);
}

// dequant 8 weights (2 packed ints, low bytes) -> short8 bf16
static __device__ __forceinline__ short8 dq8(int2 p, float xmin, float dd) {
    uint u0 = pack2_bf16(fmaf((float)(p.x & 3), dd, xmin),
                         fmaf((float)((p.x >> 2) & 3), dd, xmin));
    uint u1 = pack2_bf16(fmaf((float)((p.x >> 4) & 3), dd, xmin),
                         fmaf((float)((p.x >> 6) & 3), dd, xmin));
    uint u2 = pack2_bf16(fmaf((float)(p.y & 3), dd, xmin),
                         fmaf((float)((p.y >> 2) & 3), dd, xmin));
    uint u3 = pack2_bf16(fmaf((float)((p.y >> 4) & 3), dd, xmin),
                         fmaf((float)((p.y >> 6) & 3), dd, xmin));
    uint4 q = make_uint4(u0, u1, u2, u3);
    short8 r;
    __builtin_memcpy(&r, &q, 16);
    return r;
}

static __device__ __forceinline__ void rng_decode(uint ru, float2 rf, int fmt,
                                                  float& xmin, float& dd) {
    float xmax;
    if (fmt == 2) {
        xmin = rf.x; xmax = rf.y;
    } else if (fmt == 1) {
        xmin = bf16_to_f((ushort)(ru & 0xffff));
        xmax = bf16_to_f((ushort)(ru >> 16));
    } else {
        __half2 h;
        __builtin_memcpy(&h, &ru, 4);
        xmin = __half2float(h.x); xmax = __half2float(h.y);
    }
    dd = (xmax - xmin) * (1.0f / 3.0f);
}

static __device__ __forceinline__ void gload16(const void* g, void* l) {
    __builtin_amdgcn_global_load_lds((const __attribute__((address_space(1))) void*)g,
                                     (__attribute__((address_space(3))) void*)l,
                                     16, 0, 0);
}

// ---------- kernel 1: fused detect + raw-stage + dequant-on-read GEMM ----------
__global__ __launch_bounds__(256, 3)
void gemm_kernel(const float* __restrict__ x,
                 const int* __restrict__ packed,
                 const void* __restrict__ rr,
                 float* __restrict__ part) {
    const int nb   = blockIdx.x;   // 0..171 (64 output cols)
    const int s    = blockIdx.y;   // 0..3   (K split: 1024 each)
    const int t    = threadIdx.x;
    const int lane = t & 63;
    const int wv   = t >> 6;

    __shared__ __align__(16) char lds[3 * WB + 2 * AB];   // 40 KiB
    __shared__ int s_viol[3];
    __shared__ int s_max[3];
    __shared__ int s_fmt;

    // ---- block-local range-dtype detection (verbatim from passing rounds) ----
    if (t < 3) { s_viol[t] = 0; s_max[t] = 0; }
    __syncthreads();
    {
        const int g = 1024 + t;   // f32-view reads bytes [8192,10240): in-bounds for all fmts
        const uint   ru = ((const uint*)rr)[g];
        const float2 rf = ((const float2*)rr)[g];
        int viol[3]; float mx[3];
        {   // h0: fp16 pairs
            __half2 h; __builtin_memcpy(&h, &ru, 4);
            const float a = __half2float(h.x), c = __half2float(h.y);
            viol[0] = !(fabsf(a) < 1.f && fabsf(c) < 1.f && a <= c);
            mx[0] = fabsf(c);
        }
        {   // h1: bf16 pairs
            const float a = bf16_to_f((ushort)(ru & 0xffff));
            const float c = bf16_to_f((ushort)(ru >> 16));
            viol[1] = !(fabsf(a) < 1.f && fabsf(c) < 1.f && a <= c);
            mx[1] = fabsf(c);
        }
        {   // h2: f32 pairs
            viol[2] = !(fabsf(rf.x) < 1.f && fabsf(rf.y) < 1.f && rf.x <= rf.y);
            mx[2] = fabsf(rf.y);
        }
#pragma unroll
        for (int h = 0; h < 3; ++h) {
            if (viol[h]) atomicOr(&s_viol[h], 1);
            atomicMax(&s_max[h], __float_as_int(mx[h]));
        }
    }
    __syncthreads();
    if (t == 0) {
        const float lo = 0.02f;
        int f = 0;
        if      (!s_viol[2] && __int_as_float(s_max[2]) > lo) f = 2;
        else if (!s_viol[1] && __int_as_float(s_max[1]) > lo) f = 1;
        s_fmt = f;
    }
    __syncthreads();
    const int fmt = s_fmt;   // uniform across block

    // ---- per-block K-step rotation: de-phase the packed fetch stream ----
    // All step-indexed accesses use ((it + rot) & 7); accumulation order within
    // a split changes (FP-reorder only). Co-resident blocks now touch different
    // 128-B k-windows concurrently -> address bits 7-11 fully covered.
    const int rot = (nb * 3 + s) & 7;

    // ---- W staging: lane covers rows {wv*8 + lane>>3, +32}, 16 B each ----
    // Global source pre-swizzled within the 128-B window; LDS dest linear
    // (gload_lds: wave-uniform base + lane*16). Involution matches read XOR.
    const int sr0 = wv * 8 + (lane >> 3);
    const int sr1 = sr0 + 32;
    const char* gw0 = (const char*)packed + (size_t)(nb * BN + sr0) * 4096 + s * 1024
                      + (uint)(((lane & 7) * 16) ^ ((sr0 & 7) << 4));
    const char* gw1 = (const char*)packed + (size_t)(nb * BN + sr1) * 4096 + s * 1024
                      + (uint)(((lane & 7) * 16) ^ ((sr1 & 7) << 4));

    // ---- A staging (write): thread covers x row t>>3, 16 f32 at col (t&7)*16 ----
    const float* xsrc = x + (t >> 3) * IN_F + s * 1024 + (t & 7) * 16;
    const uint aswz = (uint)(((t >> 3) & 7) << 4);
    const uint acb  = (uint)((t & 7) * 32);

    // ---- consumers ----
    const int r = lane & 15;           // C col within 16 / A row (acc0)
    const int j = lane >> 4;           // k-slice (k = j*8 .. +8)
    const int nrow = (wv << 4) | r;    // W row this lane dequants
    const int n    = nb * BN + nrow;
    const uint arsw = (uint)((r & 7) << 4);
    const uint rsw  = (uint)((nrow & 7) << 4);
    const int rngidx = n * 32;
    const uint*   rr_u  = (const uint*)rr;
    const float2* rr_f2 = (const float2*)rr;
    const int kb0 = s * KSTEPS;

    char* wbufA = lds;                 // read target (iter i)
    char* wbufB = lds + WB;            // stage target (iter i+1)
    char* wbufC = lds + 2 * WB;
    char* abuf0 = lds + 3 * WB;
    char* abuf1 = abuf0 + AB;

    f32x4 acc0 = {0.f, 0.f, 0.f, 0.f};
    f32x4 acc1 = {0.f, 0.f, 0.f, 0.f};

    // ---- prologue: stage rotated step 0 (gloads FIRST), then its reg loads ----
    {
        const int s0 = rot;
        gload16(gw0 + s0 * 128, wbufA + wv * 1024);
        gload16(gw1 + s0 * 128, wbufA + 4096 + wv * 1024);
    }
    uint  ruc = 0; float2 rfc = {0.f, 0.f};
    if (fmt == 2) rfc = rr_f2[rngidx + kb0 + rot];
    else          ruc = rr_u[rngidx + kb0 + rot];
    float4 xc0, xc1, xc2, xc3;
    {
        const float* xs = xsrc + rot * 128;
        xc0 = *(const float4*)(xs);
        xc1 = *(const float4*)(xs + 4);
        xc2 = *(const float4*)(xs + 8);
        xc3 = *(const float4*)(xs + 12);
    }

#pragma unroll 1
    for (int it = 0; it < KSTEPS; ++it) {
        // (1) stage W(it+1) -> wbufB (wrap-around at it=7: harmless reload)
        const int stn = (it + 1 + rot) & (KSTEPS - 1);
        gload16(gw0 + stn * 128, wbufB + wv * 1024);
        gload16(gw1 + stn * 128, wbufB + 4096 + wv * 1024);

        // (2) reg loads for it+1: ranges + x slice
        uint  run = 0; float2 rfn = {0.f, 0.f};
        if (fmt == 2) rfn = rr_f2[rngidx + kb0 + stn];
        else          run = rr_u[rngidx + kb0 + stn];
        const float* xs = xsrc + stn * 128;
        float4 xn0 = *(const float4*)(xs);
        float4 xn1 = *(const float4*)(xs + 4);
        float4 xn2 = *(const float4*)(xs + 8);
        float4 xn3 = *(const float4*)(xs + 12);

        // (3) pack current x slice -> A tile (bf16, swizzled)
        {
            char* at = (it & 1) ? abuf1 : abuf0;
            uint q0 = pack2_bf16(xc0.x, xc0.y), q1 = pack2_bf16(xc0.z, xc0.w);
            uint q2 = pack2_bf16(xc1.x, xc1.y), q3 = pack2_bf16(xc1.z, xc1.w);
            uint q4 = pack2_bf16(xc2.x, xc2.y), q5 = pack2_bf16(xc2.z, xc2.w);
            uint q6 = pack2_bf16(xc3.x, xc3.y), q7 = pack2_bf16(xc3.z, xc3.w);
            char* adst = at + (t >> 3) * 256;
            *(uint4*)(adst + (acb ^ aswz))        = make_uint4(q0, q1, q2, q3);
            *(uint4*)(adst + ((acb + 16) ^ aswz)) = make_uint4(q4, q5, q6, q7);
        }

        // (4) handoff: drain LDS writes; allow exactly this iter's 7 VMEM ops
        //     ({2 gload, 4 xf, 1 rng} of it+1) to stay in flight across barrier.
        asm volatile("s_waitcnt lgkmcnt(0) vmcnt(7)" ::: "memory");
        __builtin_amdgcn_s_barrier();
        __builtin_amdgcn_sched_barrier(0);

        // (5) dequant-on-read + MFMA
        {
            const char* at  = (it & 1) ? abuf1 : abuf0;
            const char* as0 = at + r * 256;
            const char* as1 = as0 + 16 * 256;
            const char* wt  = wbufA + nrow * 128;
            float xmin, dd;
            rng_decode(ruc, rfc, fmt, xmin, dd);
#pragma unroll
            for (int kc = 0; kc < 4; ++kc) {
                const uint ao = (uint)((kc << 6) | (j << 4));
                short8 av0 = *(const short8*)(as0 + (ao ^ arsw));
                short8 av1 = *(const short8*)(as1 + (ao ^ arsw));
                const int2 pq = *(const int2*)(wt + ((uint)((kc << 5) | (j << 3)) ^ rsw));
                const short8 bf = dq8(pq, xmin, dd);
                acc0 = __builtin_amdgcn_mfma_f32_16x16x32_bf16(av0, bf, acc0, 0, 0, 0);
                acc1 = __builtin_amdgcn_mfma_f32_16x16x32_bf16(av1, bf, acc1, 0, 0, 0);
            }
        }

        // (6) rotate registers and LDS buffers
        ruc = run; rfc = rfn;
        xc0 = xn0; xc1 = xn1; xc2 = xn2; xc3 = xn3;
        char* tmp = wbufA; wbufA = wbufB; wbufB = wbufC; wbufC = tmp;
    }

    // ---- epilogue: split-K partial stores ----
    // C/D layout col=lane&15, row=(lane>>4)*4+reg (m89-verified)
    float* pout = part + (size_t)s * (32 * OUT_F);
    const int r0 = j << 2;
#pragma unroll
    for (int v = 0; v < 4; ++v) {
        pout[(r0 + v) * OUT_F + n]      = acc0[v];
        pout[(16 + r0 + v) * OUT_F + n] = acc1[v];
    }
}

// ---------- kernel 2: out = bias + sum of split-K partials ----------
__global__ __launch_bounds__(256)
void reduce_kernel(const float* __restrict__ part,
                   const float* __restrict__ bias,
                   float* __restrict__ out) {
    const int i = blockIdx.x * 256 + threadIdx.x;   // 0..88063 float4 units
    const int n4 = i % 2752;                        // 11008/4
    const float4* p4 = (const float4*)part;
    float4 a = ((const float4*)bias)[n4];
#pragma unroll
    for (int ss = 0; ss < SPLITS; ++ss) {
        const float4 v = p4[ss * 88064 + i];
        a.x += v.x; a.y += v.y; a.z += v.z; a.w += v.w;
    }
    ((float4*)out)[i] = a;
}

extern "C" void kernel_launch(void* const* d_in, const int* in_sizes, int n_in,
                              void* d_out, int out_size, void* d_ws, size_t ws_size,
                              hipStream_t stream) {
    const float* x      = (const float*)d_in[0];
    const int*   packed = (const int*)d_in[1];
    const void*  rr     = (const void*)d_in[2];
    const float* bias   = (const float*)d_in[3];
    float*       out    = (float*)d_out;
    float*       part   = (float*)d_ws;   // 4*32*11008 f32 = 5.6 MB

    gemm_kernel<<<dim3(NB, SPLITS), 256, 0, stream>>>(x, packed, rr, part);
    reduce_kernel<<<344, 256, 0, stream>>>(part, bias, out);
}